// Round 7
// baseline (184.846 us; speedup 1.0000x reference)
//
#include <hip/hip_runtime.h>
#include <stdint.h>

// ---------------------------------------------------------------------------
// CrossAttention_43061342110469 — algebraic reduction:
// einsum('bvhd,bhqk->bvhd', v, softmax(scores)) == v * L  (softmax rows sum
// to 1; summed over q gives L=2048). So out = 2048*(x @ Wv @ Wo) + const.
//
// R5 (2nd resubmission; container infra failed twice on this source, audit
// found no HW-fault path): gemm_main rebuilt as a latency-hiding pipeline
// (R4 counters: MfmaUtil 14% / VALUBusy 25% / occupancy 15% -> latency-bound)
//   * 128x64 tiles -> grid 1024 = 4 blocks/CU (was 2)
//   * A (x, fp32->bf16 fused) double-buffered in LDS; next-iter loads issued
//     before this iter's MFMAs, packed+written after -> 1 barrier/iter
//   * B (Wt, 2MB, L2-resident) read straight to registers one iter ahead --
//     no B LDS, no B staging drain
//   * even/odd unroll with named buffers (no runtime-indexed reg arrays)
// wgemm (K1) unchanged from R3 for clean attribution.
// ---------------------------------------------------------------------------

typedef __attribute__((ext_vector_type(8))) short bf16x8;
typedef __attribute__((ext_vector_type(4))) float f32x4;

typedef __attribute__((address_space(1))) void as1_void;
typedef __attribute__((address_space(3))) void as3_void;
#define GLD16(g, s)                                                          \
  __builtin_amdgcn_global_load_lds((as1_void*)(g), (as3_void*)(s), 16, 0, 0)

__device__ __forceinline__ short f2bf(float f) {
  union { float f; uint32_t u; } v; v.f = f;
  uint32_t r = v.u + 0x7FFFu + ((v.u >> 16) & 1u);  // round-to-nearest-even
  return (short)(r >> 16);
}

// pack 8 fp32 -> bf16x8 (+0x8000, take high16 via v_perm)
__device__ __forceinline__ bf16x8 pack8(f32x4 a, f32x4 b) {
  union { f32x4 f; uint32_t u[4]; } x, y;
  x.f = a; y.f = b;
#pragma unroll
  for (int t = 0; t < 4; ++t) x.u[t] += 0x8000u;
#pragma unroll
  for (int t = 0; t < 4; ++t) y.u[t] += 0x8000u;
  union { bf16x8 v; uint32_t u[4]; } o;
  o.u[0] = __builtin_amdgcn_perm(x.u[1], x.u[0], 0x07060302);
  o.u[1] = __builtin_amdgcn_perm(x.u[3], x.u[2], 0x07060302);
  o.u[2] = __builtin_amdgcn_perm(y.u[1], y.u[0], 0x07060302);
  o.u[3] = __builtin_amdgcn_perm(y.u[3], y.u[2], 0x07060302);
  return o.v;
}

// ---- K1: blocks [0,512): Wt = 2048*(Wv@Wo)^T with in-kernel Wo transpose;
//          blocks [512,576): biasc[n] = 2048*sum_k bv[k]*Wo[k,n] + bo[n].
// (unchanged from R3)
__global__ __launch_bounds__(256) void wgemm(
    const float* __restrict__ Wo, const float* __restrict__ Wv,
    const float* __restrict__ bv, const float* __restrict__ bo,
    short* __restrict__ Wt, float* __restrict__ biasc) {
  constexpr int BK = 64, NW = 1024;  // NW = row stride of Wo / Wv / Wt
  __shared__ __align__(16) float Bsf[64 * BK];  // 16 KB fp32 (Wv tile)
  __shared__ __align__(16) float Ts[64 * 36];   //  9 KB fp32 (Wo^T stage)
  const int b = blockIdx.x, tid = threadIdx.x;

  if (b >= 512) {  // ---- bias blocks
    float* red = Bsf;
    const int b3 = b - 512;
    const int nx = tid & 15, ky = tid >> 4;
    const int n = b3 * 16 + nx;
    float s = 0.f;
    for (int k = ky; k < 1024; k += 16)
      s += bv[k] * Wo[(size_t)k * NW + n];
    red[tid] = s;
    __syncthreads();
#pragma unroll
    for (int st = 128; st >= 16; st >>= 1) {
      if (tid < st) red[tid] += red[tid + st];
      __syncthreads();
    }
    if (ky == 0) biasc[n] = 2048.0f * red[nx] + bo[n];
    return;
  }

  // ---- gemm blocks: bm = n-tile (Wo cols), bn = k-tile (Wv rows)
  const int lane = tid & 63, wave = tid >> 6;
  const int bm = (b >> 4) * 32, bn = (b & 15) * 64;
  const int wm = (wave & 1) * 16, wn = (wave >> 1) * 32;
  const int l15 = lane & 15, quad = lane >> 4;

  f32x4 acc[2];
  acc[0] = (f32x4){0.f, 0.f, 0.f, 0.f};
  acc[1] = (f32x4){0.f, 0.f, 0.f, 0.f};

  // B (fp32): 64 rows x 16 chunks(16B) = 1024 chunks, 4/thread, XOR swizzle
  const int br = tid >> 4, bc4 = (tid & 15) ^ (br & 7);
  const float* pb = Wv + (size_t)(bn + br) * NW + bc4 * 4;
  float* lb = Bsf + tid * 4;

  // A (Wo transpose-stage): rows j = tid>>3 (+32), cols bm + (tid&7)*4
  const int ajr = tid >> 3, ac4 = (tid & 7) * 4;
  const float* pa = Wo + (size_t)ajr * NW + bm + ac4;

  for (int kt = 0; kt < 1024; kt += BK) {
    float4 va = *(const float4*)(pa);
    float4 vb = *(const float4*)(pa + 32 * (size_t)NW);
    pa += (size_t)BK * NW;
#pragma unroll
    for (int s = 0; s < 4; ++s) GLD16(pb + (size_t)(16 * s) * NW, lb + 1024 * s);
    pb += BK;
    *(float4*)(Ts + ajr * 36 + ac4) = va;
    *(float4*)(Ts + (ajr + 32) * 36 + ac4) = vb;
    __syncthreads();
#pragma unroll
    for (int kk = 0; kk < 2; ++kk) {
      // A-frag: n-row = wm+l15, j = (kk*4+quad)*8 + e  (column read of Ts)
      const float* tsp = Ts + ((kk * 4 + quad) * 8) * 36 + wm + l15;
      float av[8];
#pragma unroll
      for (int e = 0; e < 8; ++e) av[e] = tsp[e * 36];
      bf16x8 af = pack8((f32x4){av[0], av[1], av[2], av[3]},
                        (f32x4){av[4], av[5], av[6], av[7]});
#pragma unroll
      for (int j = 0; j < 2; ++j) {
        const int rn = wn + j * 16 + l15;
        const int c4 = kk * 8 + quad * 2;
        f32x4 u0 = *(const f32x4*)(Bsf + (rn * 16 + (c4 ^ (rn & 7))) * 4);
        f32x4 u1 = *(const f32x4*)(Bsf + (rn * 16 + ((c4 + 1) ^ (rn & 7))) * 4);
        acc[j] = __builtin_amdgcn_mfma_f32_16x16x32_bf16(af, pack8(u0, u1),
                                                         acc[j], 0, 0, 0);
      }
    }
    __syncthreads();
  }
#pragma unroll
  for (int j = 0; j < 2; ++j) {
    const int col = bn + wn + j * 16 + l15;   // k-dim
    const int row0 = bm + wm + quad * 4;      // n-dim
#pragma unroll
    for (int r = 0; r < 4; ++r)
      Wt[(size_t)(row0 + r) * NW + col] = f2bf(2048.f * acc[j][r]);
  }
}

// ---- K2: out = x @ Wt^T + biasc; 128x64 tile, dbuf-A pipeline -------------
// grid 1024 = 64 M-tiles x 16 N-tiles; bm = b&63 -> all 16 N-tiles of one
// x-panel share XCD (b%8). 4 blocks/CU; 1 barrier per K-step.
// Per iter: issue next A fp32 loads + next B reg loads -> compute (ds_read
// A + 16 MFMA with B regs) -> pack+ds_write next A -> barrier.
__global__ __launch_bounds__(256, 4) void gemm_main(
    const float* __restrict__ X, const short* __restrict__ Bt,
    const float* __restrict__ bias, float* __restrict__ Out,
    int M, int N, int K) {
  constexpr int BK = 64;
  __shared__ __align__(16) char smem[32768];  // As0 16K + As1 16K
  short* As0 = (short*)smem;
  short* As1 = (short*)(smem + 16384);
  const int tid = threadIdx.x, lane = tid & 63, wave = tid >> 6;
  const int b = blockIdx.x;
  const int bm = (b & 63) * 128;
  const int bn = (b >> 6) * 64;
  const int wm = (wave & 1) * 64, wn = (wave >> 1) * 32;
  const int l15 = lane & 15, quad = lane >> 4;

  f32x4 acc[4][2];
#pragma unroll
  for (int i = 0; i < 4; ++i)
#pragma unroll
    for (int j = 0; j < 2; ++j) acc[i][j] = (f32x4){0.f, 0.f, 0.f, 0.f};

  // A staging (XOR chunk swizzle): thread -> row srow(+32s), 8 floats at sc8
  const int srow = tid >> 3, sc8 = (tid & 7) ^ (srow & 7);
  const float* pa = X + (size_t)(bm + srow) * K + sc8 * 8;
  short* la0 = As0 + tid * 8;
  short* la1 = As1 + tid * 8;

  // B reg-load bases: frag(kk,j) = Bt[(bn+wn+j*16+l15)*K + kt + (kk*4+quad)*8]
  const short* pb0 = Bt + (size_t)(bn + wn + l15) * K + quad * 8;
  const short* pb1 = pb0 + 16 * (size_t)K;

  float4 a0[4], a1[4];
  bf16x8 Bc[4], Bn[4];

#define LOADA(kt)                                                            \
  {                                                                          \
    _Pragma("unroll") for (int s = 0; s < 4; ++s) {                          \
      const float* p = pa + (size_t)(32 * s) * K + (kt);                     \
      a0[s] = *(const float4*)(p);                                           \
      a1[s] = *(const float4*)(p + 4);                                       \
    }                                                                        \
  }
#define LOADB(Br, kt)                                                        \
  {                                                                          \
    Br[0] = *(const bf16x8*)(pb0 + (kt));                                    \
    Br[1] = *(const bf16x8*)(pb1 + (kt));                                    \
    Br[2] = *(const bf16x8*)(pb0 + (kt) + 32);                               \
    Br[3] = *(const bf16x8*)(pb1 + (kt) + 32);                               \
  }
#define PACKWRITE(la)                                                        \
  {                                                                          \
    _Pragma("unroll") for (int s = 0; s < 4; ++s)                            \
        *(bf16x8*)((la) + 2048 * s) =                                        \
            pack8((f32x4){a0[s].x, a0[s].y, a0[s].z, a0[s].w},               \
                  (f32x4){a1[s].x, a1[s].y, a1[s].z, a1[s].w});              \
  }
#define COMPUTE(As, Br)                                                      \
  {                                                                          \
    _Pragma("unroll") for (int kk = 0; kk < 2; ++kk) {                       \
      bf16x8 af[4];                                                          \
      _Pragma("unroll") for (int i = 0; i < 4; ++i) {                        \
        const int r = wm + i * 16 + l15;                                     \
        af[i] =                                                              \
            *(const bf16x8*)((As) + r * BK + ((kk * 4 + quad) ^ (r & 7)) * 8);\
      }                                                                      \
      _Pragma("unroll") for (int i = 0; i < 4; ++i)                          \
          _Pragma("unroll") for (int j = 0; j < 2; ++j)                      \
              acc[i][j] = __builtin_amdgcn_mfma_f32_16x16x32_bf16(           \
                  af[i], Br[kk * 2 + j], acc[i][j], 0, 0, 0);                \
    }                                                                        \
  }

  // prologue: stage iter 0 (kt=0) into As0 / Bc
  LOADA(0);
  LOADB(Bc, 0);
  PACKWRITE(la0);
  __syncthreads();

  // 8 trips x 2 iters; kt_even = trip*128, kt_odd = trip*128+64
  for (int trip = 0; trip < 8; ++trip) {
    const int kt_o = trip * 128 + 64;
    // even iter: compute As0/Bc, prefetch kt_o -> As1/Bn
    LOADA(kt_o);
    LOADB(Bn, kt_o);
    COMPUTE(As0, Bc);
    PACKWRITE(la1);
    __syncthreads();
    // odd iter: compute As1/Bn, prefetch next even -> As0/Bc
    if (trip < 7) {
      const int kt_n = trip * 128 + 128;
      LOADA(kt_n);
      LOADB(Bc, kt_n);
      COMPUTE(As1, Bn);
      PACKWRITE(la0);
    } else {
      COMPUTE(As1, Bn);
    }
    __syncthreads();
  }
#undef LOADA
#undef LOADB
#undef PACKWRITE
#undef COMPUTE

  // epilogue: MFMA C layout (col=l15, row=quad*4+r) -> per-wave LDS tile
  // (16 x 32 used, stride 36) -> full-line float4 stores (same-wave only).
  float* T = (float*)smem + wave * 576;  // 16 rows x 36 stride
#pragma unroll
  for (int i = 0; i < 4; ++i) {
#pragma unroll
    for (int j = 0; j < 2; ++j) {
      const float bb = bias[bn + wn + j * 16 + l15];
#pragma unroll
      for (int r = 0; r < 4; ++r)
        T[(quad * 4 + r) * 36 + j * 16 + l15] = acc[i][j][r] + bb;
    }
#pragma unroll
    for (int c = 0; c < 2; ++c) {
      const int row = (lane >> 3) + 8 * c;
      f32x4 v = *(const f32x4*)(T + row * 36 + (lane & 7) * 4);
      *(f32x4*)(Out + (size_t)(bm + wm + i * 16 + row) * N + bn + wn +
                (lane & 7) * 4) = v;
    }
  }
}

extern "C" void kernel_launch(void* const* d_in, const int* in_sizes, int n_in,
                              void* d_out, int out_size, void* d_ws,
                              size_t ws_size, hipStream_t stream) {
  // setup_inputs order: x, encoder_x, Wq, bq, Wk, bk, Wv, bv, Wo, bo
  const float* x  = (const float*)d_in[0];
  const float* Wv = (const float*)d_in[6];
  const float* bv = (const float*)d_in[7];
  const float* Wo = (const float*)d_in[8];
  const float* bo = (const float*)d_in[9];
  float* out = (float*)d_out;

  constexpr int D = 1024, NO = 1024;  // NO = H*QKV
  constexpr int M = 8192;             // B*L

  char* ws = (char*)d_ws;
  short* wt_bf = (short*)(ws);              // 2 MB: 2048*(Wv@Wo)^T bf16
  float* biasc = (float*)(ws + (2u << 20)); // 4 KB: fused bias

  wgemm<<<576, 256, 0, stream>>>(Wo, Wv, bv, bo, wt_bf, biasc);
  gemm_main<<<(M / 128) * (NO / 64), 256, 0, stream>>>(
      x, wt_bf, biasc, out, M, NO, D);
}

// Round 8
// 166.921 us; speedup vs baseline: 1.1074x; 1.1074x over previous
//
#include <hip/hip_runtime.h>
#include <stdint.h>

// ---------------------------------------------------------------------------
// CrossAttention_43061342110469 — algebraic reduction:
// einsum('bvhd,bhqk->bvhd', v, softmax(scores)) == v * L  (softmax rows sum
// to 1; summed over q gives L=2048). So out = 2048*(x @ Wv @ Wo) + const.
//
// R8: post-mortem of R5 regression (occ 35% but VGPR 60, VALUBusy halved ->
// launch_bounds(256,4) squeezed regalloc, prefetch sunk to just-in-time;
// 128x64 tiles doubled staging work). Fix: R4's 128x128 tile + full dbuf
// (As x2 + Bs x2 = 64KB), ONE barrier/iter, A(t+1) in regs + GLD16 B(t+1)
// issued BEFORE compute(t), pack+write after -> latency under 32 MFMAs.
// Plain launch_bounds(256) so prefetch regs stay live. Grid 512 (2/CU,
// grid-bound, same as R4 -> only the schedule differs).
// wgemm (K1) unchanged from R3 for clean attribution.
// ---------------------------------------------------------------------------

typedef __attribute__((ext_vector_type(8))) short bf16x8;
typedef __attribute__((ext_vector_type(4))) float f32x4;

typedef __attribute__((address_space(1))) void as1_void;
typedef __attribute__((address_space(3))) void as3_void;
#define GLD16(g, s)                                                          \
  __builtin_amdgcn_global_load_lds((as1_void*)(g), (as3_void*)(s), 16, 0, 0)

__device__ __forceinline__ short f2bf(float f) {
  union { float f; uint32_t u; } v; v.f = f;
  uint32_t r = v.u + 0x7FFFu + ((v.u >> 16) & 1u);  // round-to-nearest-even
  return (short)(r >> 16);
}

// pack 8 fp32 -> bf16x8 (+0x8000, take high16 via v_perm)
__device__ __forceinline__ bf16x8 pack8(f32x4 a, f32x4 b) {
  union { f32x4 f; uint32_t u[4]; } x, y;
  x.f = a; y.f = b;
#pragma unroll
  for (int t = 0; t < 4; ++t) x.u[t] += 0x8000u;
#pragma unroll
  for (int t = 0; t < 4; ++t) y.u[t] += 0x8000u;
  union { bf16x8 v; uint32_t u[4]; } o;
  o.u[0] = __builtin_amdgcn_perm(x.u[1], x.u[0], 0x07060302);
  o.u[1] = __builtin_amdgcn_perm(x.u[3], x.u[2], 0x07060302);
  o.u[2] = __builtin_amdgcn_perm(y.u[1], y.u[0], 0x07060302);
  o.u[3] = __builtin_amdgcn_perm(y.u[3], y.u[2], 0x07060302);
  return o.v;
}

// ---- K1: blocks [0,512): Wt = 2048*(Wv@Wo)^T with in-kernel Wo transpose;
//          blocks [512,576): biasc[n] = 2048*sum_k bv[k]*Wo[k,n] + bo[n].
// (unchanged from R3)
__global__ __launch_bounds__(256) void wgemm(
    const float* __restrict__ Wo, const float* __restrict__ Wv,
    const float* __restrict__ bv, const float* __restrict__ bo,
    short* __restrict__ Wt, float* __restrict__ biasc) {
  constexpr int BK = 64, NW = 1024;  // NW = row stride of Wo / Wv / Wt
  __shared__ __align__(16) float Bsf[64 * BK];  // 16 KB fp32 (Wv tile)
  __shared__ __align__(16) float Ts[64 * 36];   //  9 KB fp32 (Wo^T stage)
  const int b = blockIdx.x, tid = threadIdx.x;

  if (b >= 512) {  // ---- bias blocks
    float* red = Bsf;
    const int b3 = b - 512;
    const int nx = tid & 15, ky = tid >> 4;
    const int n = b3 * 16 + nx;
    float s = 0.f;
    for (int k = ky; k < 1024; k += 16)
      s += bv[k] * Wo[(size_t)k * NW + n];
    red[tid] = s;
    __syncthreads();
#pragma unroll
    for (int st = 128; st >= 16; st >>= 1) {
      if (tid < st) red[tid] += red[tid + st];
      __syncthreads();
    }
    if (ky == 0) biasc[n] = 2048.0f * red[nx] + bo[n];
    return;
  }

  // ---- gemm blocks: bm = n-tile (Wo cols), bn = k-tile (Wv rows)
  const int lane = tid & 63, wave = tid >> 6;
  const int bm = (b >> 4) * 32, bn = (b & 15) * 64;
  const int wm = (wave & 1) * 16, wn = (wave >> 1) * 32;
  const int l15 = lane & 15, quad = lane >> 4;

  f32x4 acc[2];
  acc[0] = (f32x4){0.f, 0.f, 0.f, 0.f};
  acc[1] = (f32x4){0.f, 0.f, 0.f, 0.f};

  // B (fp32): 64 rows x 16 chunks(16B) = 1024 chunks, 4/thread, XOR swizzle
  const int br = tid >> 4, bc4 = (tid & 15) ^ (br & 7);
  const float* pb = Wv + (size_t)(bn + br) * NW + bc4 * 4;
  float* lb = Bsf + tid * 4;

  // A (Wo transpose-stage): rows j = tid>>3 (+32), cols bm + (tid&7)*4
  const int ajr = tid >> 3, ac4 = (tid & 7) * 4;
  const float* pa = Wo + (size_t)ajr * NW + bm + ac4;

  for (int kt = 0; kt < 1024; kt += BK) {
    float4 va = *(const float4*)(pa);
    float4 vb = *(const float4*)(pa + 32 * (size_t)NW);
    pa += (size_t)BK * NW;
#pragma unroll
    for (int s = 0; s < 4; ++s) GLD16(pb + (size_t)(16 * s) * NW, lb + 1024 * s);
    pb += BK;
    *(float4*)(Ts + ajr * 36 + ac4) = va;
    *(float4*)(Ts + (ajr + 32) * 36 + ac4) = vb;
    __syncthreads();
#pragma unroll
    for (int kk = 0; kk < 2; ++kk) {
      // A-frag: n-row = wm+l15, j = (kk*4+quad)*8 + e  (column read of Ts)
      const float* tsp = Ts + ((kk * 4 + quad) * 8) * 36 + wm + l15;
      float av[8];
#pragma unroll
      for (int e = 0; e < 8; ++e) av[e] = tsp[e * 36];
      bf16x8 af = pack8((f32x4){av[0], av[1], av[2], av[3]},
                        (f32x4){av[4], av[5], av[6], av[7]});
#pragma unroll
      for (int j = 0; j < 2; ++j) {
        const int rn = wn + j * 16 + l15;
        const int c4 = kk * 8 + quad * 2;
        f32x4 u0 = *(const f32x4*)(Bsf + (rn * 16 + (c4 ^ (rn & 7))) * 4);
        f32x4 u1 = *(const f32x4*)(Bsf + (rn * 16 + ((c4 + 1) ^ (rn & 7))) * 4);
        acc[j] = __builtin_amdgcn_mfma_f32_16x16x32_bf16(af, pack8(u0, u1),
                                                         acc[j], 0, 0, 0);
      }
    }
    __syncthreads();
  }
#pragma unroll
  for (int j = 0; j < 2; ++j) {
    const int col = bn + wn + j * 16 + l15;   // k-dim
    const int row0 = bm + wm + quad * 4;      // n-dim
#pragma unroll
    for (int r = 0; r < 4; ++r)
      Wt[(size_t)(row0 + r) * NW + col] = f2bf(2048.f * acc[j][r]);
  }
}

// ---- K2: out = x @ Wt^T + biasc; 128x128 tile, full dbuf, 1 barrier/iter --
// grid 512 = 64 M-tiles x 8 N-tiles; bm = b&63 -> the 8 N-tiles of one
// x-panel share XCD (b%8). Per iter: issue A(t+1)->regs + GLD16 B(t+1)->
// Bs^1 BEFORE compute(t) (latency under 32 MFMA/wave), pack+write A after,
// one barrier. Plain launch_bounds so prefetch regs stay live (R5 lesson).
__global__ __launch_bounds__(256) void gemm_main(
    const float* __restrict__ X, const short* __restrict__ Bt,
    const float* __restrict__ bias, float* __restrict__ Out,
    int M, int N, int K) {
  constexpr int BK = 64;
  __shared__ __align__(16) char smem[65536];  // As0,As1,Bs0,Bs1 (16K each)
  short* As0 = (short*)smem;
  short* As1 = (short*)(smem + 16384);
  short* Bs0 = (short*)(smem + 32768);
  short* Bs1 = (short*)(smem + 49152);
  const int tid = threadIdx.x, lane = tid & 63, wave = tid >> 6;
  const int b = blockIdx.x;
  const int bm = (b & 63) * 128;
  const int bn = (b >> 6) * 128;
  const int wm = (wave & 1) * 64, wn = (wave >> 1) * 64;
  const int l15 = lane & 15, quad = lane >> 4;

  f32x4 acc[4][4];
#pragma unroll
  for (int i = 0; i < 4; ++i)
#pragma unroll
    for (int j = 0; j < 4; ++j) acc[i][j] = (f32x4){0.f, 0.f, 0.f, 0.f};

  // staging map (XOR chunk swizzle): LDS[row][c8] = global[row][c8^(row&7)]
  const int srow = tid >> 3, sc8 = (tid & 7) ^ (srow & 7);
  const float* pa = X + (size_t)(bm + srow) * K + sc8 * 8;   // fp32 x8
  const short* pb = Bt + (size_t)(bn + srow) * K + sc8 * 8;  // bf16 x8

  float4 a0[4], a1[4];

#define LOADA(kt)                                                            \
  {                                                                          \
    _Pragma("unroll") for (int s = 0; s < 4; ++s) {                          \
      const float* p = pa + (size_t)(32 * s) * K + (kt);                     \
      a0[s] = *(const float4*)(p);                                           \
      a1[s] = *(const float4*)(p + 4);                                       \
    }                                                                        \
  }
#define LOADB(Bsx, kt)                                                       \
  {                                                                          \
    _Pragma("unroll") for (int s = 0; s < 4; ++s)                            \
        GLD16(pb + (size_t)(32 * s) * K + (kt), (Bsx) + tid * 8 + 2048 * s); \
  }
#define PACKWRITE(Asx)                                                       \
  {                                                                          \
    _Pragma("unroll") for (int s = 0; s < 4; ++s)                            \
        *(bf16x8*)((Asx) + tid * 8 + 2048 * s) =                             \
            pack8((f32x4){a0[s].x, a0[s].y, a0[s].z, a0[s].w},               \
                  (f32x4){a1[s].x, a1[s].y, a1[s].z, a1[s].w});              \
  }
#define COMPUTE(Asx, Bsx)                                                    \
  {                                                                          \
    _Pragma("unroll") for (int kk = 0; kk < 2; ++kk) {                       \
      bf16x8 af[4], bfr[4];                                                  \
      _Pragma("unroll") for (int i = 0; i < 4; ++i) {                        \
        const int r = wm + i * 16 + l15;                                     \
        af[i] = *(const bf16x8*)((Asx) + r * BK +                            \
                                 ((kk * 4 + quad) ^ (r & 7)) * 8);           \
      }                                                                      \
      _Pragma("unroll") for (int j = 0; j < 4; ++j) {                        \
        const int r = wn + j * 16 + l15;                                     \
        bfr[j] = *(const bf16x8*)((Bsx) + r * BK +                           \
                                  ((kk * 4 + quad) ^ (r & 7)) * 8);          \
      }                                                                      \
      _Pragma("unroll") for (int i = 0; i < 4; ++i)                          \
          _Pragma("unroll") for (int j = 0; j < 4; ++j)                      \
              acc[i][j] = __builtin_amdgcn_mfma_f32_16x16x32_bf16(           \
                  af[i], bfr[j], acc[i][j], 0, 0, 0);                        \
    }                                                                        \
  }

  // prologue: stage iter 0 into As0/Bs0
  LOADA(0);
  LOADB(Bs0, 0);
  PACKWRITE(As0);
  __syncthreads();

  // 8 trips x 2 iters (K=1024, BK=64 -> 16 iters, last is odd -> no prefetch)
  for (int trip = 0; trip < 8; ++trip) {
    const int kt_o = trip * 128 + 64;
    // even iter: prefetch kt_o -> (regs, Bs1); compute As0/Bs0; write As1
    LOADA(kt_o);
    LOADB(Bs1, kt_o);
    COMPUTE(As0, Bs0);
    PACKWRITE(As1);
    __syncthreads();
    // odd iter: prefetch next even -> (regs, Bs0); compute As1/Bs1; write As0
    if (trip < 7) {
      const int kt_n = trip * 128 + 128;
      LOADA(kt_n);
      LOADB(Bs0, kt_n);
      COMPUTE(As1, Bs1);
      PACKWRITE(As0);
    } else {
      COMPUTE(As1, Bs1);
    }
    __syncthreads();
  }
#undef LOADA
#undef LOADB
#undef PACKWRITE
#undef COMPUTE

  // epilogue: MFMA C layout (col=l15, row=quad*4+r) -> per-wave LDS tile
  // (16 x 64, stride 68) -> full-line float4 stores. Same-wave ordering only.
  float* T = (float*)smem + wave * 1088;  // 16 rows x 68 stride
#pragma unroll
  for (int i = 0; i < 4; ++i) {
#pragma unroll
    for (int j = 0; j < 4; ++j) {
      const float bb = bias[bn + wn + j * 16 + l15];
#pragma unroll
      for (int r = 0; r < 4; ++r)
        T[(quad * 4 + r) * 68 + j * 16 + l15] = acc[i][j][r] + bb;
    }
#pragma unroll
    for (int p = 0; p < 4; ++p) {
      const int row = (lane >> 4) + 4 * p;
      const int ch = lane & 15;
      f32x4 v = *(const f32x4*)(T + row * 68 + ch * 4);
      *(f32x4*)(Out + (size_t)(bm + wm + i * 16 + row) * N + bn + wn +
                ch * 4) = v;
    }
  }
}

extern "C" void kernel_launch(void* const* d_in, const int* in_sizes, int n_in,
                              void* d_out, int out_size, void* d_ws,
                              size_t ws_size, hipStream_t stream) {
  // setup_inputs order: x, encoder_x, Wq, bq, Wk, bk, Wv, bv, Wo, bo
  const float* x  = (const float*)d_in[0];
  const float* Wv = (const float*)d_in[6];
  const float* bv = (const float*)d_in[7];
  const float* Wo = (const float*)d_in[8];
  const float* bo = (const float*)d_in[9];
  float* out = (float*)d_out;

  constexpr int D = 1024, NO = 1024;  // NO = H*QKV
  constexpr int M = 8192;             // B*L

  char* ws = (char*)d_ws;
  short* wt_bf = (short*)(ws);              // 2 MB: 2048*(Wv@Wo)^T bf16
  float* biasc = (float*)(ws + (2u << 20)); // 4 KB: fused bias

  wgemm<<<576, 256, 0, stream>>>(Wo, Wv, bv, bo, wt_bf, biasc);
  gemm_main<<<(M / 128) * (NO / 128), 256, 0, stream>>>(
      x, wt_bf, biasc, out, M, NO, D);
}